// Round 9
// baseline (53.291 us; speedup 1.0000x reference)
//
#include <hip/hip_runtime.h>
#include <math.h>

#define NPTS   4096
#define BATCH  8
#define NBD    (2 * BATCH)
#define BLOCK  256
#define PN     2                  // p points per thread
#define MCHUNK 512                // q points per block-scan
#define NG     (MCHUNK / 4)       // 128 groups of 4 q points
#define NTILE  (BLOCK * PN)       // 512 n per block
#define NBLK   (NPTS / NTILE)     // 8
#define NCHUNK (NPTS / MCHUNK)    // 8
#define PTS_PER_SRC (BATCH * NPTS)   // 32768

// Prep: transform every point (both arrays) to (-2px, -2py, -2pz, |p|^2).
// q4t layout: [src(0=x,1=y)][32768]
__global__ __launch_bounds__(256) void prep_kernel(
    const float* __restrict__ x, const float* __restrict__ y,
    float4* __restrict__ q4t) {
  const int t   = blockIdx.x * 256 + threadIdx.x;  // 0..65535
  const int src = t >> 15;
  const int idx = t & (PTS_PER_SRC - 1);
  const float* p = ((src == 0) ? x : y) + 3 * (size_t)idx;
  const float a = p[0], b = p[1], c = p[2];
  q4t[t] = make_float4(-2.0f * a, -2.0f * b, -2.0f * c, a * a + b * b + c * c);
}

// Pass 1: per (bd, m-chunk, n-tile), partial min of
// t = |q|^2 - 2 p.q  (q read as wave-uniform float4 -> scalar/SMEM path,
// no LDS, no barrier); store mn + |p|^2. bd = b*2+dir; dir0: p=x,q=y.
__global__ __launch_bounds__(BLOCK) void partial_min_kernel(
    const float* __restrict__ x, const float* __restrict__ y,
    const float4* __restrict__ q4t, float* __restrict__ part) {
  const int bd  = blockIdx.z;
  const int b   = bd >> 1;
  const int dir = bd & 1;

  const float* Pb = ((dir == 0) ? x : y) + (size_t)b * NPTS * 3;
  // q comes from the OTHER array's transformed table
  const float4* Qc = q4t + (size_t)((dir == 0) ? 1 : 0) * PTS_PER_SRC
                          + (size_t)b * NPTS + (size_t)blockIdx.y * MCHUNK;

  const int n0 = blockIdx.x * NTILE + threadIdx.x;
  float px[PN], py[PN], pz[PN], p2[PN], mn[PN];
#pragma unroll
  for (int i = 0; i < PN; ++i) {
    const int n = n0 + i * BLOCK;
    px[i] = Pb[3 * n + 0];
    py[i] = Pb[3 * n + 1];
    pz[i] = Pb[3 * n + 2];
    p2[i] = px[i] * px[i] + py[i] * py[i] + pz[i] * pz[i];
    mn[i] = 3.4e38f;
  }

#pragma unroll 2
  for (int g = 0; g < NG; ++g) {
    // Uniform (blockIdx/loop-only) addresses -> scalar loads, SMEM pipe.
    const float4 a0 = Qc[4 * g + 0];
    const float4 a1 = Qc[4 * g + 1];
    const float4 a2 = Qc[4 * g + 2];
    const float4 a3 = Qc[4 * g + 3];
#pragma unroll
    for (int i = 0; i < PN; ++i) {
      const float t0 = fmaf(px[i], a0.x, fmaf(py[i], a0.y, fmaf(pz[i], a0.z, a0.w)));
      const float t1 = fmaf(px[i], a1.x, fmaf(py[i], a1.y, fmaf(pz[i], a1.z, a1.w)));
      const float t2 = fmaf(px[i], a2.x, fmaf(py[i], a2.y, fmaf(pz[i], a2.z, a2.w)));
      const float t3 = fmaf(px[i], a3.x, fmaf(py[i], a3.y, fmaf(pz[i], a3.z, a3.w)));
      mn[i] = fminf(fminf(t0, t1), fminf(fminf(t2, t3), mn[i]));  // min + min3
    }
  }

  float* wp = part + ((size_t)bd * NCHUNK + blockIdx.y) * NPTS + n0;
#pragma unroll
  for (int i = 0; i < PN; ++i)
    wp[i * BLOCK] = mn[i] + p2[i];
}

// Pass 2: one block per bd; min across chunks per n (float4, coalesced), max.
__global__ __launch_bounds__(BLOCK) void reduce1_kernel(
    const float* __restrict__ part, float* __restrict__ bdmax) {
  const int bd = blockIdx.x;
  const float4* base = (const float4*)(part + (size_t)bd * NCHUNK * NPTS);

  float mx = 0.0f;
  for (int v = threadIdx.x; v < NPTS / 4; v += BLOCK) {
    float4 mn4 = base[v];
#pragma unroll
    for (int c = 1; c < NCHUNK; ++c) {
      const float4 t = base[(size_t)c * (NPTS / 4) + v];
      mn4.x = fminf(mn4.x, t.x);
      mn4.y = fminf(mn4.y, t.y);
      mn4.z = fminf(mn4.z, t.z);
      mn4.w = fminf(mn4.w, t.w);
    }
    mx = fmaxf(mx, fmaxf(fmaxf(mn4.x, mn4.y), fmaxf(mn4.z, mn4.w)));
  }
  for (int off = 32; off > 0; off >>= 1)
    mx = fmaxf(mx, __shfl_down(mx, off));

  __shared__ float w[BLOCK / 64];
  if ((threadIdx.x & 63) == 0) w[threadIdx.x >> 6] = mx;
  __syncthreads();
  if (threadIdx.x == 0) {
    float m = w[0];
#pragma unroll
    for (int i = 1; i < BLOCK / 64; ++i) m = fmaxf(m, w[i]);
    bdmax[bd] = m;
  }
}

// Pass 3: combine directions, sqrt, mean.
__global__ void reduce2_kernel(const float* __restrict__ bdmax,
                               float* __restrict__ out) {
  if (threadIdx.x == 0) {
    float s = 0.0f;
#pragma unroll
    for (int b = 0; b < BATCH; ++b)
      s += sqrtf(fmaxf(fmaxf(bdmax[2 * b], bdmax[2 * b + 1]), 0.0f));
    out[0] = s / (float)BATCH;
  }
}

extern "C" void kernel_launch(void* const* d_in, const int* in_sizes, int n_in,
                              void* d_out, int out_size, void* d_ws, size_t ws_size,
                              hipStream_t stream) {
  const float* x = (const float*)d_in[0];
  const float* y = (const float*)d_in[1];
  float4* q4t  = (float4*)d_ws;                            // 2*32768 float4 = 1 MB
  float*  part = (float*)(q4t + 2 * PTS_PER_SRC);          // 16*8*4096 floats = 2 MB
  float*  bdmax = part + (size_t)NBD * NCHUNK * NPTS;      // 16 floats
  float*  out = (float*)d_out;

  prep_kernel<<<2 * PTS_PER_SRC / 256, 256, 0, stream>>>(x, y, q4t);
  dim3 grid(NBLK, NCHUNK, NBD);  // (8, 8, 16) = 1024 blocks
  partial_min_kernel<<<grid, BLOCK, 0, stream>>>(x, y, q4t, part);
  reduce1_kernel<<<NBD, BLOCK, 0, stream>>>(part, bdmax);
  reduce2_kernel<<<1, 64, 0, stream>>>(bdmax, out);
}

// Round 10
// 34.067 us; speedup vs baseline: 1.5643x; 1.5643x over previous
//
#include <hip/hip_runtime.h>
#include <math.h>

#define NPTS   4096
#define BATCH  8
#define NBD    (2 * BATCH)
#define BLOCK  256
#define PN     8                  // p points per thread (halves LDS reads/pair)
#define MCHUNK 128                // q points staged per block
#define NTILE  (BLOCK * PN)       // 2048 n per block
#define NBLK   (NPTS / NTILE)     // 2
#define NCHUNK (NPTS / MCHUNK)    // 32
#define NSPLIT 8                  // reduce1 n-split

// Pass 1: per (bd, m-chunk, n-tile), partial min over the chunk of
// t = |q|^2 - 2 p.q  (q pre-transformed in LDS: one float4 = one
// ds_read_b128 per q-point per wave); store mn + |p|^2.
// Pure-scalar fmaf formulation — the only one that matches its slot model.
// bd = b*2 + dir. dir 0: p=x, q=y; dir 1: p=y, q=x.
__global__ __launch_bounds__(BLOCK) void partial_min_kernel(
    const float* __restrict__ x, const float* __restrict__ y,
    float* __restrict__ part) {
  const int bd  = blockIdx.z;
  const int b   = bd >> 1;
  const int dir = bd & 1;

  const float* Pb = ((dir == 0) ? x : y) + (size_t)b * NPTS * 3;
  const float* Qb = ((dir == 0) ? y : x) + (size_t)b * NPTS * 3
                    + (size_t)blockIdx.y * MCHUNK * 3;

  __shared__ float4 qs[MCHUNK];  // (-2qx, -2qy, -2qz, |q|^2)
  if (threadIdx.x < MCHUNK) {
    const int m = threadIdx.x;
    const float gx = Qb[3 * m + 0], gy = Qb[3 * m + 1], gz = Qb[3 * m + 2];
    qs[m] = make_float4(-2.0f * gx, -2.0f * gy, -2.0f * gz,
                        gx * gx + gy * gy + gz * gz);
  }
  __syncthreads();

  const int n0 = blockIdx.x * NTILE + threadIdx.x;
  float px[PN], py[PN], pz[PN], p2[PN], mn[PN];
#pragma unroll
  for (int i = 0; i < PN; ++i) {
    const int n = n0 + i * BLOCK;
    px[i] = Pb[3 * n + 0];
    py[i] = Pb[3 * n + 1];
    pz[i] = Pb[3 * n + 2];
    p2[i] = px[i] * px[i] + py[i] * py[i] + pz[i] * pz[i];
    mn[i] = 3.4e38f;
  }

#pragma unroll 2
  for (int g = 0; g < MCHUNK; g += 4) {
    const float4 q0 = qs[g + 0];  // uniform addr -> broadcast ds_read_b128
    const float4 q1 = qs[g + 1];
    const float4 q2 = qs[g + 2];
    const float4 q3 = qs[g + 3];
#pragma unroll
    for (int i = 0; i < PN; ++i) {
      const float t0 = fmaf(px[i], q0.x, fmaf(py[i], q0.y, fmaf(pz[i], q0.z, q0.w)));
      const float t1 = fmaf(px[i], q1.x, fmaf(py[i], q1.y, fmaf(pz[i], q1.z, q1.w)));
      const float t2 = fmaf(px[i], q2.x, fmaf(py[i], q2.y, fmaf(pz[i], q2.z, q2.w)));
      const float t3 = fmaf(px[i], q3.x, fmaf(py[i], q3.y, fmaf(pz[i], q3.z, q3.w)));
      // two fusable min3 trees: min3(t0,t1,t2), then min3(t3, mn, .)
      mn[i] = fminf(fminf(t3, mn[i]), fminf(fminf(t0, t1), t2));
    }
  }

  float* wp = part + ((size_t)bd * NCHUNK + blockIdx.y) * NPTS + n0;
#pragma unroll
  for (int i = 0; i < PN; ++i)
    wp[i * BLOCK] = mn[i] + p2[i];
}

// Pass 2: grid (NSPLIT, NBD); each block: 512 n's x 32 chunks ->
// min across chunks per n (float4, coalesced), max over its n-range.
__global__ __launch_bounds__(128) void reduce1_kernel(
    const float* __restrict__ part, float* __restrict__ bd2) {
  const int split = blockIdx.x;
  const int bd    = blockIdx.y;
  const float4* base = (const float4*)(part + (size_t)bd * NCHUNK * NPTS);
  const int v = split * (NPTS / 4 / NSPLIT) + threadIdx.x;  // 128 vec4 / block

  float4 mn4 = base[v];
#pragma unroll
  for (int c = 1; c < NCHUNK; ++c) {
    const float4 t = base[(size_t)c * (NPTS / 4) + v];
    mn4.x = fminf(mn4.x, t.x);
    mn4.y = fminf(mn4.y, t.y);
    mn4.z = fminf(mn4.z, t.z);
    mn4.w = fminf(mn4.w, t.w);
  }
  float mx = fmaxf(fmaxf(mn4.x, mn4.y), fmaxf(mn4.z, mn4.w));
  for (int off = 32; off > 0; off >>= 1)
    mx = fmaxf(mx, __shfl_down(mx, off));

  __shared__ float w[2];
  if ((threadIdx.x & 63) == 0) w[threadIdx.x >> 6] = mx;
  __syncthreads();
  if (threadIdx.x == 0) bd2[bd * NSPLIT + split] = fmaxf(w[0], w[1]);
}

// Pass 3: combine splits + directions, clamp, sqrt, mean.
__global__ __launch_bounds__(64) void reduce2_kernel(
    const float* __restrict__ bd2, float* __restrict__ out) {
  __shared__ float d2s[NBD];
  if (threadIdx.x < NBD) {
    float m = bd2[threadIdx.x * NSPLIT];
#pragma unroll
    for (int s = 1; s < NSPLIT; ++s)
      m = fmaxf(m, bd2[threadIdx.x * NSPLIT + s]);
    d2s[threadIdx.x] = fmaxf(m, 0.0f);
  }
  __syncthreads();
  if (threadIdx.x == 0) {
    float s = 0.0f;
#pragma unroll
    for (int b = 0; b < BATCH; ++b)
      s += sqrtf(fmaxf(d2s[2 * b], d2s[2 * b + 1]));
    out[0] = s / (float)BATCH;
  }
}

extern "C" void kernel_launch(void* const* d_in, const int* in_sizes, int n_in,
                              void* d_out, int out_size, void* d_ws, size_t ws_size,
                              hipStream_t stream) {
  const float* x = (const float*)d_in[0];
  const float* y = (const float*)d_in[1];
  float* part = (float*)d_ws;                        // 16*32*4096 floats = 8 MB
  float* bd2  = part + (size_t)NBD * NCHUNK * NPTS;  // NBD*NSPLIT floats
  float* out  = (float*)d_out;

  dim3 grid(NBLK, NCHUNK, NBD);  // (2, 32, 16) = 1024 blocks, 4/CU
  partial_min_kernel<<<grid, BLOCK, 0, stream>>>(x, y, part);
  reduce1_kernel<<<dim3(NSPLIT, NBD), 128, 0, stream>>>(part, bd2);
  reduce2_kernel<<<1, 64, 0, stream>>>(bd2, out);
}